// Round 4
// baseline (1073.148 us; speedup 1.0000x reference)
//
#include <hip/hip_runtime.h>
#include <math.h>

#define DD 128

// ---------------- CSR build ----------------
__global__ void k_hist(const int* __restrict__ dst, int* __restrict__ deg, int E){
    int i = blockIdx.x*256 + threadIdx.x;
    if (i < E) atomicAdd(&deg[dst[i]], 1);
}

__global__ void k_chunksum(const int* __restrict__ deg, int* __restrict__ csum,
                           float* __restrict__ invdeg, int n){
    __shared__ int sdata[256];
    int t = threadIdx.x;
    int i0 = blockIdx.x*512 + t*2;
    int a = (i0     < n) ? deg[i0]   : 0;
    int b = (i0 + 1 < n) ? deg[i0+1] : 0;
    if (i0     < n) invdeg[i0]   = 1.0f / (float)max(a, 1);
    if (i0 + 1 < n) invdeg[i0+1] = 1.0f / (float)max(b, 1);
    sdata[t] = a + b; __syncthreads();
    for (int off = 128; off > 0; off >>= 1){
        if (t < off) sdata[t] += sdata[t+off];
        __syncthreads();
    }
    if (t == 0) csum[blockIdx.x] = sdata[0];
}

__global__ void k_scanchunks(int* __restrict__ csum, int nchunks, int* __restrict__ row_ptr, int n){
    if (threadIdx.x == 0){
        int acc = 0;
        for (int i = 0; i < nchunks; i++){ int v = csum[i]; csum[i] = acc; acc += v; }
        row_ptr[n] = acc;
    }
}

__global__ void k_scanwithin(const int* __restrict__ deg, const int* __restrict__ csum,
                             int* __restrict__ row_ptr, int n){
    __shared__ int s[256];
    int t = threadIdx.x;
    int i0 = blockIdx.x*512 + t*2;
    int a = (i0     < n) ? deg[i0]   : 0;
    int b = (i0 + 1 < n) ? deg[i0+1] : 0;
    int tsum = a + b;
    s[t] = tsum; __syncthreads();
    for (int off = 1; off < 256; off <<= 1){
        int v = (t >= off) ? s[t-off] : 0;
        __syncthreads();
        s[t] += v;
        __syncthreads();
    }
    int excl = s[t] - tsum + csum[blockIdx.x];
    if (i0     < n) row_ptr[i0]   = excl;
    if (i0 + 1 < n) row_ptr[i0+1] = excl + a;
}

__global__ void k_fill(const int* __restrict__ src, const int* __restrict__ dst,
                       const int* __restrict__ row_ptr, int* __restrict__ cursor,
                       int* __restrict__ sorted_src, int E){
    int i = blockIdx.x*256 + threadIdx.x;
    if (i < E){
        int d = dst[i];
        int p = atomicAdd(&cursor[d], 1);
        sorted_src[row_ptr[d] + p] = src[i];
    }
}

// ---------------- row-wise scalings (wave per row, fp32) ----------------
// MODE 0: log_map from origin: scale = (2/sc)*atanh(sc*n)/n, n=max(||x||,1e-10)
// MODE 1: l2norm: scale = 1/max(||x||,1e-12)
// NOTE: no __restrict__ — called in-place (per-thread pure, safe).
template<int MODE>
__global__ void k_rowscale(const float* in, float* out, int n_rows, const float* cptr){
    int wid = (blockIdx.x*256 + threadIdx.x) >> 6;
    if (wid >= n_rows) return;
    int lane = threadIdx.x & 63;
    const float2 v = *(const float2*)(in + (size_t)wid*DD + lane*2);
    float ss = v.x*v.x + v.y*v.y;
    #pragma unroll
    for (int m = 32; m > 0; m >>= 1) ss += __shfl_xor(ss, m, 64);
    float nrm = sqrtf(ss);
    float scale;
    if (MODE == 0){
        float c  = cptr[0];
        c = (c > 0.f && c < 1e30f) ? c : 1.0f;       // sanity guard (no-op normally)
        float sc = sqrtf(c);
        float n2 = fmaxf(nrm, 1e-10f);
        float a  = fminf(sc*n2, 0.99999994f);        // atanh domain guard (no-op normally)
        scale = (2.0f/sc) * atanhf(a) / n2;
    } else {
        scale = 1.0f / fmaxf(nrm, 1e-12f);
    }
    *(float2*)(out + (size_t)wid*DD + lane*2) = make_float2(v.x*scale, v.y*scale);
}

// ---------------- GEMM: Y[r][c] = sum_k X[r][k]*W[c][k] + bias[c]  (all fp32) ----------------
// 32 rows/block, 256 threads. W staged in two 64-wide k-phases, LDS stride 65
// (bank = col + k mod 32 -> conflict-free col-parallel reads). X staged fp32,
// reads are 2-address wave broadcasts (free). Total LDS = 33.3 + 16.4 = 49.7 KB.
// In-place safe (Y may == X): each block stages its own 32 rows before writing them.
__global__ __launch_bounds__(256, 2)
void k_gemm(const float* X, const float* __restrict__ W,
            const float* __restrict__ bias, float* Y, int n_rows){
    __shared__ float sW[DD*65];     // 33280 B (one 64-wide k phase)
    __shared__ float sX[32*DD];     // 16384 B
    int t = threadIdx.x;
    int row0 = blockIdx.x * 32;

    // stage X (full 128 k)
    #pragma unroll
    for (int i = 0; i < 4; i++){
        int idx = i*256 + t;            // 1024 float4 = 32 rows x 128 floats
        int r   = idx >> 5;
        int k4  = idx & 31;
        int gr  = row0 + r;
        float4 xv = (gr < n_rows) ? ((const float4*)(X + (size_t)gr*DD))[k4]
                                  : make_float4(0.f,0.f,0.f,0.f);
        *(float4*)(sX + r*DD + k4*4) = xv;
    }

    int rg = t >> 5, cg = t & 31;
    float acc[4][4];
    #pragma unroll
    for (int i = 0; i < 4; i++)
        #pragma unroll
        for (int j = 0; j < 4; j++) acc[i][j] = 0.f;

    for (int ph = 0; ph < 2; ph++){
        __syncthreads();
        // stage W[c][ph*64 .. ph*64+63] : 2048 float4
        #pragma unroll
        for (int i = 0; i < 8; i++){
            int idx = i*256 + t;
            int c   = idx >> 4;          // 16 float4 per row-chunk
            int k4  = idx & 15;
            float4 wv = *(const float4*)(W + (size_t)c*DD + ph*64 + k4*4);
            float* dp = sW + c*65 + k4*4;
            dp[0] = wv.x; dp[1] = wv.y; dp[2] = wv.z; dp[3] = wv.w;
        }
        __syncthreads();

        #pragma unroll 4
        for (int k0 = 0; k0 < 64; k0 += 4){
            float4 xr[4];
            #pragma unroll
            for (int i = 0; i < 4; i++)
                xr[i] = *(const float4*)(sX + (rg*4 + i)*DD + ph*64 + k0);
            #pragma unroll
            for (int j = 0; j < 4; j++){
                int col = cg + 32*j;
                const float* wp = sW + col*65 + k0;
                float w0 = wp[0], w1 = wp[1], w2 = wp[2], w3 = wp[3];
                #pragma unroll
                for (int i = 0; i < 4; i++){
                    acc[i][j] = fmaf(xr[i].x, w0, acc[i][j]);
                    acc[i][j] = fmaf(xr[i].y, w1, acc[i][j]);
                    acc[i][j] = fmaf(xr[i].z, w2, acc[i][j]);
                    acc[i][j] = fmaf(xr[i].w, w3, acc[i][j]);
                }
            }
        }
    }

    #pragma unroll
    for (int i = 0; i < 4; i++){
        int gr = row0 + rg*4 + i;
        if (gr < n_rows){
            #pragma unroll
            for (int j = 0; j < 4; j++){
                int col = cg + 32*j;
                Y[(size_t)gr*DD + col] = acc[i][j] + bias[col];
            }
        }
    }
}

// ---------------- fused mean-aggregate + epilogue (wave per node, fp32) ----------------
// MODE 0: LeakyReLU(0.2)  MODE 1: exp_map from origin  MODE 2: l2norm
template<int MODE>
__global__ void k_agg(const float* __restrict__ h,
                      const int* __restrict__ row_ptr, const int* __restrict__ sorted_src,
                      const float* __restrict__ invdeg,
                      float* __restrict__ outbuf, int n_rows, const float* __restrict__ cptr){
    int wid = (blockIdx.x*256 + threadIdx.x) >> 6;
    if (wid >= n_rows) return;
    int lane = threadIdx.x & 63;
    int beg = row_ptr[wid], end = row_ptr[wid+1];
    float ax = 0.f, ay = 0.f;
    int off = lane*2;
    for (int j = beg; j < end; j++){
        int s = sorted_src[j];
        s = min(max(s, 0), n_rows - 1);              // OOB guard (no-op when CSR correct)
        s = __builtin_amdgcn_readfirstlane(s);
        const float2 v = *(const float2*)(h + (size_t)s*DD + off);
        ax += v.x; ay += v.y;
    }
    float inv = invdeg[wid];
    ax *= inv; ay *= inv;
    float ox, oy;
    if (MODE == 0){
        ox = ax > 0.f ? ax : 0.2f*ax;
        oy = ay > 0.f ? ay : 0.2f*ay;
    } else {
        float ss = ax*ax + ay*ay;
        #pragma unroll
        for (int m = 32; m > 0; m >>= 1) ss += __shfl_xor(ss, m, 64);
        float nrm = sqrtf(ss);
        float scale;
        if (MODE == 1){
            float c  = cptr[0];
            c = (c > 0.f && c < 1e30f) ? c : 1.0f;
            float sc = sqrtf(c);
            float n2 = fmaxf(nrm, 1e-10f);
            scale = tanhf(sc*n2*0.5f) / (sc*n2);
        } else {
            scale = 1.0f / fmaxf(nrm, 1e-12f);
        }
        ox = ax*scale; oy = ay*scale;
    }
    *(float2*)(outbuf + (size_t)wid*DD + off) = make_float2(ox, oy);
}

extern "C" void kernel_launch(void* const* d_in, const int* in_sizes, int n_in,
                              void* d_out, int out_size, void* d_ws, size_t ws_size,
                              hipStream_t stream){
    const int*   src = (const int*)d_in[0];
    const int*   dst = (const int*)d_in[1];
    const float* emb_in[3] = {(const float*)d_in[2], (const float*)d_in[3], (const float*)d_in[4]};
    const float* W_in[3]   = {(const float*)d_in[5], (const float*)d_in[7], (const float*)d_in[9]};
    const float* b_in[3]   = {(const float*)d_in[6], (const float*)d_in[8], (const float*)d_in[10]};
    const float* b_c       = (const float*)d_in[11];
    // d_in[12] (s_curvature) unused by the reference

    const int E  = in_sizes[0];
    const int ND = in_sizes[2];
    const int N  = ND / DD;
    const int Lnum = in_sizes[5] / (DD*DD);
    const int nchunks = (N + 511) / 512;

    char* w = (char*)d_ws;
    auto alloc = [&](size_t bytes)->char*{
        char* p = w; w += (bytes + 255) & ~(size_t)255; return p;
    };
    float* h         = (float*)alloc((size_t)ND*4);         // GEMM scratch (fp32)
    float* invdeg    = (float*)alloc((size_t)N*4);
    int*   deg       = (int*)  alloc((size_t)N*4);
    int*   row_ptr   = (int*)  alloc((size_t)(N+1)*4);
    int*   cursor    = (int*)  alloc((size_t)N*4);
    int*   csum      = (int*)  alloc((size_t)nchunks*4);
    int*   sorted_src= (int*)  alloc((size_t)E*4);
    (void)ws_size; (void)n_in; (void)out_size;

    // states live in d_out (fully overwritten every layer)
    float* out_e = (float*)d_out;
    float* out_b = out_e + ND;
    float* out_s = out_e + 2*ND;

    hipMemsetAsync(deg,    0, (size_t)N*4, stream);
    hipMemsetAsync(cursor, 0, (size_t)N*4, stream);

    const int TB = 256;
    // CSR build (reused by all 6 aggregations)
    k_hist<<<(E+TB-1)/TB, TB, 0, stream>>>(dst, deg, E);
    k_chunksum<<<nchunks, 256, 0, stream>>>(deg, csum, invdeg, N);
    k_scanchunks<<<1, 64, 0, stream>>>(csum, nchunks, row_ptr, N);
    k_scanwithin<<<nchunks, 256, 0, stream>>>(deg, csum, row_ptr, N);
    k_fill<<<(E+TB-1)/TB, TB, 0, stream>>>(src, dst, row_ptr, cursor, sorted_src, E);

    const int rowblocks  = (N + 3) / 4;      // 4 waves per 256-thread block
    const int gemmblocks = (N + 31) / 32;

    const float* se = emb_in[0];
    const float* sb = emb_in[1];
    const float* ss = emb_in[2];

    for (int l = 0; l < Lnum; l++){
        // Euclidean: h = se @ W^T + b ; mean-agg ; LeakyReLU -> out_e
        k_gemm<<<gemmblocks, 256, 0, stream>>>(se, W_in[0] + (size_t)l*DD*DD,
                                               b_in[0] + (size_t)l*DD, h, N);
        k_agg<0><<<rowblocks, 256, 0, stream>>>(h, row_ptr, sorted_src, invdeg, out_e, N, b_c);
        se = out_e;

        // Hyperbolic: tangent = logmap0(sb) -> h ; GEMM in-place ; mean-agg+expmap0 -> out_b
        k_rowscale<0><<<rowblocks, 256, 0, stream>>>(sb, h, N, b_c);
        k_gemm<<<gemmblocks, 256, 0, stream>>>(h, W_in[1] + (size_t)l*DD*DD,
                                               b_in[1] + (size_t)l*DD, h, N);
        k_agg<1><<<rowblocks, 256, 0, stream>>>(h, row_ptr, sorted_src, invdeg, out_b, N, b_c);
        sb = out_b;

        // Spherical: l2norm -> h ; GEMM in-place ; l2norm in-place ; mean-agg+l2norm -> out_s
        k_rowscale<1><<<rowblocks, 256, 0, stream>>>(ss, h, N, b_c);
        k_gemm<<<gemmblocks, 256, 0, stream>>>(h, W_in[2] + (size_t)l*DD*DD,
                                               b_in[2] + (size_t)l*DD, h, N);
        k_rowscale<1><<<rowblocks, 256, 0, stream>>>(h, h, N, b_c);
        k_agg<2><<<rowblocks, 256, 0, stream>>>(h, row_ptr, sorted_src, invdeg, out_s, N, b_c);
        ss = out_s;   // <-- the round-2 bug: spherical state was never advanced
    }
}

// Round 5
// 701.772 us; speedup vs baseline: 1.5292x; 1.5292x over previous
//
#include <hip/hip_runtime.h>
#include <math.h>

#define DD 128
typedef unsigned int   u32;
typedef unsigned short u16;

__device__ __forceinline__ float lo2f(u32 p){ return __uint_as_float(p << 16); }
__device__ __forceinline__ float hi2f(u32 p){ return __uint_as_float(p & 0xFFFF0000u); }
__device__ __forceinline__ u16 f2bf(float f){
    u32 u = __float_as_uint(f);
    return (u16)((u + 0x7fffu + ((u >> 16) & 1u)) >> 16);   // RNE
}

// ---------------- CSR build ----------------
__global__ void k_hist(const int* __restrict__ dst, int* __restrict__ deg, int E){
    int i = blockIdx.x*256 + threadIdx.x;
    if (i < E) atomicAdd(&deg[dst[i]], 1);
}

__global__ void k_chunksum(const int* __restrict__ deg, int* __restrict__ csum,
                           float* __restrict__ invdeg, int n){
    __shared__ int sdata[256];
    int t = threadIdx.x;
    int i0 = blockIdx.x*512 + t*2;
    int a = (i0     < n) ? deg[i0]   : 0;
    int b = (i0 + 1 < n) ? deg[i0+1] : 0;
    if (i0     < n) invdeg[i0]   = 1.0f / (float)max(a, 1);
    if (i0 + 1 < n) invdeg[i0+1] = 1.0f / (float)max(b, 1);
    sdata[t] = a + b; __syncthreads();
    for (int off = 128; off > 0; off >>= 1){
        if (t < off) sdata[t] += sdata[t+off];
        __syncthreads();
    }
    if (t == 0) csum[blockIdx.x] = sdata[0];
}

__global__ void k_scanchunks(int* __restrict__ csum, int nchunks, int* __restrict__ row_ptr, int n){
    if (threadIdx.x == 0){
        int acc = 0;
        for (int i = 0; i < nchunks; i++){ int v = csum[i]; csum[i] = acc; acc += v; }
        row_ptr[n] = acc;
    }
}

__global__ void k_scanwithin(const int* __restrict__ deg, const int* __restrict__ csum,
                             int* __restrict__ row_ptr, int n){
    __shared__ int s[256];
    int t = threadIdx.x;
    int i0 = blockIdx.x*512 + t*2;
    int a = (i0     < n) ? deg[i0]   : 0;
    int b = (i0 + 1 < n) ? deg[i0+1] : 0;
    int tsum = a + b;
    s[t] = tsum; __syncthreads();
    for (int off = 1; off < 256; off <<= 1){
        int v = (t >= off) ? s[t-off] : 0;
        __syncthreads();
        s[t] += v;
        __syncthreads();
    }
    int excl = s[t] - tsum + csum[blockIdx.x];
    if (i0     < n) row_ptr[i0]   = excl;
    if (i0 + 1 < n) row_ptr[i0+1] = excl + a;
}

__global__ void k_fill(const int* __restrict__ src, const int* __restrict__ dst,
                       const int* __restrict__ row_ptr, int* __restrict__ cursor,
                       int* __restrict__ sorted_src, int E){
    int i = blockIdx.x*256 + threadIdx.x;
    if (i < E){
        int d = dst[i];
        int p = atomicAdd(&cursor[d], 1);
        sorted_src[row_ptr[d] + p] = src[i];
    }
}

// ---------------- GEMM + fused pre/post transforms ----------------
// Y_bf16[r][c] = post( pre(X)[r] @ W[c] + bias[c] )
// PRE : 0 none | 1 logmap0 row-scale | 2 l2norm row-scale
// POST: 0 none | 1 l2norm (s-path middle norm)
// 32 rows/block, 256 threads. W staged in two 64-wide k phases, LDS stride 65.
template<int PRE, int POST>
__global__ __launch_bounds__(256, 2)
void k_gemm(const float* __restrict__ X, const float* __restrict__ W,
            const float* __restrict__ bias, u16* __restrict__ Y, int n_rows,
            const float* __restrict__ cptr){
    __shared__ float sW[DD*65];     // 33280 B
    __shared__ float sX[32*DD];     // 16384 B
    int t = threadIdx.x;
    int row0 = blockIdx.x * 32;

    // stage X (full 128 k), fused per-row pre-scale.
    // iteration i: half-wave (32 lanes) handles one full row -> shfl_xor m<32 stays in-row.
    #pragma unroll
    for (int i = 0; i < 4; i++){
        int idx = i*256 + t;            // 1024 float4 = 32 rows x 128 floats
        int r   = idx >> 5;
        int k4  = idx & 31;
        int gr  = row0 + r;
        float4 xv = (gr < n_rows) ? ((const float4*)(X + (size_t)gr*DD))[k4]
                                  : make_float4(0.f,0.f,0.f,0.f);
        if (PRE != 0){
            float ss = xv.x*xv.x + xv.y*xv.y + xv.z*xv.z + xv.w*xv.w;
            #pragma unroll
            for (int m = 16; m > 0; m >>= 1) ss += __shfl_xor(ss, m, 64);
            float nrm = sqrtf(ss);
            float scale;
            if (PRE == 1){
                float c  = cptr[0];
                c = (c > 0.f && c < 1e30f) ? c : 1.0f;
                float sc = sqrtf(c);
                float n2 = fmaxf(nrm, 1e-10f);
                float a  = fminf(sc*n2, 0.99999994f);
                scale = (2.0f/sc) * atanhf(a) / n2;
            } else {
                scale = 1.0f / fmaxf(nrm, 1e-12f);
            }
            xv.x *= scale; xv.y *= scale; xv.z *= scale; xv.w *= scale;
        }
        *(float4*)(sX + r*DD + k4*4) = xv;
    }

    int rg = t >> 5, cg = t & 31;
    float acc[4][4];
    #pragma unroll
    for (int i = 0; i < 4; i++)
        #pragma unroll
        for (int j = 0; j < 4; j++) acc[i][j] = 0.f;

    for (int ph = 0; ph < 2; ph++){
        __syncthreads();
        #pragma unroll
        for (int i = 0; i < 8; i++){
            int idx = i*256 + t;
            int c   = idx >> 4;
            int k4  = idx & 15;
            float4 wv = *(const float4*)(W + (size_t)c*DD + ph*64 + k4*4);
            float* dp = sW + c*65 + k4*4;
            dp[0] = wv.x; dp[1] = wv.y; dp[2] = wv.z; dp[3] = wv.w;
        }
        __syncthreads();

        #pragma unroll 4
        for (int k0 = 0; k0 < 64; k0 += 4){
            float4 xr[4];
            #pragma unroll
            for (int i = 0; i < 4; i++)
                xr[i] = *(const float4*)(sX + (rg*4 + i)*DD + ph*64 + k0);
            #pragma unroll
            for (int j = 0; j < 4; j++){
                int col = cg + 32*j;
                const float* wp = sW + col*65 + k0;
                float w0 = wp[0], w1 = wp[1], w2 = wp[2], w3 = wp[3];
                #pragma unroll
                for (int i = 0; i < 4; i++){
                    acc[i][j] = fmaf(xr[i].x, w0, acc[i][j]);
                    acc[i][j] = fmaf(xr[i].y, w1, acc[i][j]);
                    acc[i][j] = fmaf(xr[i].z, w2, acc[i][j]);
                    acc[i][j] = fmaf(xr[i].w, w3, acc[i][j]);
                }
            }
        }
    }

    // epilogue: +bias, optional row l2norm (32 lanes own one row), bf16 store
    float bv[4];
    #pragma unroll
    for (int j = 0; j < 4; j++) bv[j] = bias[cg + 32*j];
    #pragma unroll
    for (int i = 0; i < 4; i++){
        #pragma unroll
        for (int j = 0; j < 4; j++) acc[i][j] += bv[j];
        if (POST == 1){
            float ss = acc[i][0]*acc[i][0] + acc[i][1]*acc[i][1]
                     + acc[i][2]*acc[i][2] + acc[i][3]*acc[i][3];
            #pragma unroll
            for (int m = 16; m > 0; m >>= 1) ss += __shfl_xor(ss, m, 64);
            float scale = 1.0f / fmaxf(sqrtf(ss), 1e-12f);
            #pragma unroll
            for (int j = 0; j < 4; j++) acc[i][j] *= scale;
        }
        int gr = row0 + rg*4 + i;
        if (gr < n_rows){
            #pragma unroll
            for (int j = 0; j < 4; j++)
                Y[(size_t)gr*DD + cg + 32*j] = f2bf(acc[i][j]);
        }
    }
}

// ---------------- fused mean-aggregate + epilogue (wave per node) ----------------
// h is bf16 (u32 = 2 cols per lane). MODE 0: LeakyReLU  1: expmap0  2: l2norm
template<int MODE>
__global__ void k_agg(const u32* __restrict__ h,
                      const int* __restrict__ row_ptr, const int* __restrict__ sorted_src,
                      const float* __restrict__ invdeg,
                      float* __restrict__ outbuf, int n_rows, const float* __restrict__ cptr){
    int wid = (blockIdx.x*256 + threadIdx.x) >> 6;
    if (wid >= n_rows) return;
    int lane = threadIdx.x & 63;
    int beg = row_ptr[wid], end = row_ptr[wid+1];
    float ax = 0.f, ay = 0.f;
    for (int j0 = beg; j0 < end; j0 += 64){
        int cnt = min(64, end - j0);
        int my = (j0 + lane < end) ? sorted_src[j0 + lane] : 0;
        int k = 0;
        for (; k + 8 <= cnt; k += 8){           // 8 outstanding gathers
            u32 p0 = h[(size_t)__shfl(my, k+0, 64)*64 + lane];
            u32 p1 = h[(size_t)__shfl(my, k+1, 64)*64 + lane];
            u32 p2 = h[(size_t)__shfl(my, k+2, 64)*64 + lane];
            u32 p3 = h[(size_t)__shfl(my, k+3, 64)*64 + lane];
            u32 p4 = h[(size_t)__shfl(my, k+4, 64)*64 + lane];
            u32 p5 = h[(size_t)__shfl(my, k+5, 64)*64 + lane];
            u32 p6 = h[(size_t)__shfl(my, k+6, 64)*64 + lane];
            u32 p7 = h[(size_t)__shfl(my, k+7, 64)*64 + lane];
            ax += lo2f(p0); ay += hi2f(p0);
            ax += lo2f(p1); ay += hi2f(p1);
            ax += lo2f(p2); ay += hi2f(p2);
            ax += lo2f(p3); ay += hi2f(p3);
            ax += lo2f(p4); ay += hi2f(p4);
            ax += lo2f(p5); ay += hi2f(p5);
            ax += lo2f(p6); ay += hi2f(p6);
            ax += lo2f(p7); ay += hi2f(p7);
        }
        for (; k < cnt; k++){
            u32 p = h[(size_t)__shfl(my, k, 64)*64 + lane];
            ax += lo2f(p); ay += hi2f(p);
        }
    }
    float inv = invdeg[wid];
    ax *= inv; ay *= inv;
    float ox, oy;
    if (MODE == 0){
        ox = ax > 0.f ? ax : 0.2f*ax;
        oy = ay > 0.f ? ay : 0.2f*ay;
    } else {
        float ss = ax*ax + ay*ay;
        #pragma unroll
        for (int m = 32; m > 0; m >>= 1) ss += __shfl_xor(ss, m, 64);
        float nrm = sqrtf(ss);
        float scale;
        if (MODE == 1){
            float c  = cptr[0];
            c = (c > 0.f && c < 1e30f) ? c : 1.0f;
            float sc = sqrtf(c);
            float n2 = fmaxf(nrm, 1e-10f);
            scale = tanhf(sc*n2*0.5f) / (sc*n2);
        } else {
            scale = 1.0f / fmaxf(nrm, 1e-12f);
        }
        ox = ax*scale; oy = ay*scale;
    }
    *(float2*)(outbuf + (size_t)wid*DD + lane*2) = make_float2(ox, oy);
}

extern "C" void kernel_launch(void* const* d_in, const int* in_sizes, int n_in,
                              void* d_out, int out_size, void* d_ws, size_t ws_size,
                              hipStream_t stream){
    const int*   src = (const int*)d_in[0];
    const int*   dst = (const int*)d_in[1];
    const float* emb_in[3] = {(const float*)d_in[2], (const float*)d_in[3], (const float*)d_in[4]};
    const float* W_in[3]   = {(const float*)d_in[5], (const float*)d_in[7], (const float*)d_in[9]};
    const float* b_in[3]   = {(const float*)d_in[6], (const float*)d_in[8], (const float*)d_in[10]};
    const float* b_c       = (const float*)d_in[11];

    const int E  = in_sizes[0];
    const int ND = in_sizes[2];
    const int N  = ND / DD;
    const int Lnum = in_sizes[5] / (DD*DD);
    const int nchunks = (N + 511) / 512;

    char* w = (char*)d_ws;
    auto alloc = [&](size_t bytes)->char*{
        char* p = w; w += (bytes + 255) & ~(size_t)255; return p;
    };
    u32*   h         = (u32*)  alloc((size_t)ND*2);     // bf16 h table
    float* invdeg    = (float*)alloc((size_t)N*4);
    int*   deg       = (int*)  alloc((size_t)N*4);
    int*   row_ptr   = (int*)  alloc((size_t)(N+1)*4);
    int*   cursor    = (int*)  alloc((size_t)N*4);
    int*   csum      = (int*)  alloc((size_t)nchunks*4);
    int*   sorted_src= (int*)  alloc((size_t)E*4);
    (void)ws_size; (void)n_in; (void)out_size;

    float* out_e = (float*)d_out;
    float* out_b = out_e + ND;
    float* out_s = out_e + 2*ND;

    hipMemsetAsync(deg,    0, (size_t)N*4, stream);
    hipMemsetAsync(cursor, 0, (size_t)N*4, stream);

    const int TB = 256;
    k_hist<<<(E+TB-1)/TB, TB, 0, stream>>>(dst, deg, E);
    k_chunksum<<<nchunks, 256, 0, stream>>>(deg, csum, invdeg, N);
    k_scanchunks<<<1, 64, 0, stream>>>(csum, nchunks, row_ptr, N);
    k_scanwithin<<<nchunks, 256, 0, stream>>>(deg, csum, row_ptr, N);
    k_fill<<<(E+TB-1)/TB, TB, 0, stream>>>(src, dst, row_ptr, cursor, sorted_src, E);

    const int rowblocks  = (N + 3) / 4;
    const int gemmblocks = (N + 31) / 32;

    const float* se = emb_in[0];
    const float* sb = emb_in[1];
    const float* ss = emb_in[2];

    for (int l = 0; l < Lnum; l++){
        // Euclidean
        k_gemm<0,0><<<gemmblocks, 256, 0, stream>>>(se, W_in[0] + (size_t)l*DD*DD,
                                                    b_in[0] + (size_t)l*DD, (u16*)h, N, b_c);
        k_agg<0><<<rowblocks, 256, 0, stream>>>(h, row_ptr, sorted_src, invdeg, out_e, N, b_c);
        se = out_e;
        // Hyperbolic (logmap fused into staging)
        k_gemm<1,0><<<gemmblocks, 256, 0, stream>>>(sb, W_in[1] + (size_t)l*DD*DD,
                                                    b_in[1] + (size_t)l*DD, (u16*)h, N, b_c);
        k_agg<1><<<rowblocks, 256, 0, stream>>>(h, row_ptr, sorted_src, invdeg, out_b, N, b_c);
        sb = out_b;
        // Spherical (pre-norm fused into staging, mid-norm fused into epilogue)
        k_gemm<2,1><<<gemmblocks, 256, 0, stream>>>(ss, W_in[2] + (size_t)l*DD*DD,
                                                    b_in[2] + (size_t)l*DD, (u16*)h, N, b_c);
        k_agg<2><<<rowblocks, 256, 0, stream>>>(h, row_ptr, sorted_src, invdeg, out_s, N, b_c);
        ss = out_s;
    }
}

// Round 6
// 580.661 us; speedup vs baseline: 1.8481x; 1.2086x over previous
//
#include <hip/hip_runtime.h>
#include <math.h>

#define DD 128
typedef unsigned int   u32;
typedef unsigned short u16;
typedef short bf16x8 __attribute__((ext_vector_type(8)));
typedef float f32x4  __attribute__((ext_vector_type(4)));

__device__ __forceinline__ float lo2f(u32 p){ return __uint_as_float(p << 16); }
__device__ __forceinline__ float hi2f(u32 p){ return __uint_as_float(p & 0xFFFF0000u); }
__device__ __forceinline__ u16 f2bf(float f){
    u32 u = __float_as_uint(f);
    return (u16)((u + 0x7fffu + ((u >> 16) & 1u)) >> 16);   // RNE
}

// ---------------- CSR build ----------------
__global__ void k_hist(const int* __restrict__ dst, int* __restrict__ deg, int E){
    int i = blockIdx.x*256 + threadIdx.x;
    if (i < E) atomicAdd(&deg[dst[i]], 1);
}

__global__ void k_chunksum(const int* __restrict__ deg, int* __restrict__ csum,
                           float* __restrict__ invdeg, int n){
    __shared__ int sdata[256];
    int t = threadIdx.x;
    int i0 = blockIdx.x*512 + t*2;
    int a = (i0     < n) ? deg[i0]   : 0;
    int b = (i0 + 1 < n) ? deg[i0+1] : 0;
    if (i0     < n) invdeg[i0]   = 1.0f / (float)max(a, 1);
    if (i0 + 1 < n) invdeg[i0+1] = 1.0f / (float)max(b, 1);
    sdata[t] = a + b; __syncthreads();
    for (int off = 128; off > 0; off >>= 1){
        if (t < off) sdata[t] += sdata[t+off];
        __syncthreads();
    }
    if (t == 0) csum[blockIdx.x] = sdata[0];
}

__global__ void k_scanchunks(int* __restrict__ csum, int nchunks, int* __restrict__ row_ptr, int n){
    if (threadIdx.x == 0){
        int acc = 0;
        for (int i = 0; i < nchunks; i++){ int v = csum[i]; csum[i] = acc; acc += v; }
        row_ptr[n] = acc;
    }
}

__global__ void k_scanwithin(const int* __restrict__ deg, const int* __restrict__ csum,
                             int* __restrict__ row_ptr, int n){
    __shared__ int s[256];
    int t = threadIdx.x;
    int i0 = blockIdx.x*512 + t*2;
    int a = (i0     < n) ? deg[i0]   : 0;
    int b = (i0 + 1 < n) ? deg[i0+1] : 0;
    int tsum = a + b;
    s[t] = tsum; __syncthreads();
    for (int off = 1; off < 256; off <<= 1){
        int v = (t >= off) ? s[t-off] : 0;
        __syncthreads();
        s[t] += v;
        __syncthreads();
    }
    int excl = s[t] - tsum + csum[blockIdx.x];
    if (i0     < n) row_ptr[i0]   = excl;
    if (i0 + 1 < n) row_ptr[i0+1] = excl + a;
}

__global__ void k_fill(const int* __restrict__ src, const int* __restrict__ dst,
                       const int* __restrict__ row_ptr, int* __restrict__ cursor,
                       int* __restrict__ sorted_src, int E){
    int i = blockIdx.x*256 + threadIdx.x;
    if (i < E){
        int d = dst[i];
        int p = atomicAdd(&cursor[d], 1);
        sorted_src[row_ptr[d] + p] = src[i];
    }
}

// W fp32 -> bf16 table
__global__ void k_w2b(const float* __restrict__ in, u16* __restrict__ out, int n){
    int i = blockIdx.x*256 + threadIdx.x;
    if (i < n) out[i] = f2bf(in[i]);
}

// ---------------- MFMA GEMM + fused pre/post transforms ----------------
// Y_bf16[r][c] = post( pre(X)[r] @ Wb[c] + bias[c] )
// PRE : 0 none | 1 logmap0 row-scale | 2 l2norm row-scale   (fp32, pre-cvt)
// POST: 0 none | 1 l2norm (s-path middle norm, fp32 on acc)
// Block = 256 thr = 4 waves; M=64/block (16/wave), N=128, K=128.
// A-frag: lane(m=lane&15,q=lane>>4) holds X[row m][k=c*32+q*8 .. +7] (2x float4 direct).
// B-frag: lane holds Wb[col n=lane&15 of tile][same k pattern] (ushort4 direct, L2-hot).
// C/D: col=lane&15, row=q*4+reg.
template<int PRE, int POST>
__global__ __launch_bounds__(256, 4)
void k_gemm_mfma(const float* __restrict__ X, const u16* __restrict__ Wb,
                 const float* __restrict__ bias, u16* __restrict__ Y, int n_rows,
                 const float* __restrict__ cptr){
    int t = threadIdx.x;
    int wave = t >> 6, lane = t & 63;
    int q = lane >> 4, m = lane & 15;
    int rowbase = blockIdx.x*64 + wave*16;
    int gr = min(rowbase + m, n_rows - 1);

    // load this lane's X slice: 4 chunks x 8 floats
    float4 xv[8];
    const float4* xp = (const float4*)(X + (size_t)gr*DD);
    #pragma unroll
    for (int c = 0; c < 4; c++){
        xv[2*c]   = xp[c*8 + q*2];
        xv[2*c+1] = xp[c*8 + q*2 + 1];
    }

    float scale = 1.0f;
    if (PRE != 0){
        float ss = 0.f;
        #pragma unroll
        for (int i = 0; i < 8; i++)
            ss += xv[i].x*xv[i].x + xv[i].y*xv[i].y + xv[i].z*xv[i].z + xv[i].w*xv[i].w;
        ss += __shfl_xor(ss, 16, 64);
        ss += __shfl_xor(ss, 32, 64);          // full 128-elem row norm
        float nrm = sqrtf(ss);
        if (PRE == 1){
            float c  = cptr[0];
            c = (c > 0.f && c < 1e30f) ? c : 1.0f;
            float sc = sqrtf(c);
            float n2 = fmaxf(nrm, 1e-10f);
            float a  = fminf(sc*n2, 0.99999994f);
            scale = (2.0f/sc) * atanhf(a) / n2;
        } else {
            scale = 1.0f / fmaxf(nrm, 1e-12f);
        }
    }

    bf16x8 af[4];
    #pragma unroll
    for (int c = 0; c < 4; c++){
        const float* xf = (const float*)&xv[2*c];
        #pragma unroll
        for (int j = 0; j < 8; j++) af[c][j] = (short)f2bf(xf[j]*scale);
    }

    f32x4 acc[8];
    #pragma unroll
    for (int tl = 0; tl < 8; tl++) acc[tl] = (f32x4){0.f,0.f,0.f,0.f};

    const u16* wb = Wb + (size_t)m*DD + q*8;   // + tile*16*DD + c*32
    #pragma unroll
    for (int c = 0; c < 4; c++){
        #pragma unroll
        for (int tl = 0; tl < 8; tl++){
            bf16x8 bfr = *(const bf16x8*)(wb + (size_t)tl*16*DD + c*32);
            acc[tl] = __builtin_amdgcn_mfma_f32_16x16x32_bf16(af[c], bfr, acc[tl], 0, 0, 0);
        }
    }

    // epilogue: +bias (fp32), optional row l2norm (fp32), bf16 store
    #pragma unroll
    for (int tl = 0; tl < 8; tl++){
        float bv = bias[tl*16 + m];
        #pragma unroll
        for (int r = 0; r < 4; r++) acc[tl][r] += bv;
    }
    if (POST == 1){
        float ssr[4] = {0.f,0.f,0.f,0.f};
        #pragma unroll
        for (int tl = 0; tl < 8; tl++)
            #pragma unroll
            for (int r = 0; r < 4; r++) ssr[r] += acc[tl][r]*acc[tl][r];
        #pragma unroll
        for (int r = 0; r < 4; r++){
            float s = ssr[r];
            s += __shfl_xor(s, 1, 64);
            s += __shfl_xor(s, 2, 64);
            s += __shfl_xor(s, 4, 64);
            s += __shfl_xor(s, 8, 64);         // sum over the 16 col-lanes (same q)
            float sc = 1.0f / fmaxf(sqrtf(s), 1e-12f);
            #pragma unroll
            for (int tl = 0; tl < 8; tl++) acc[tl][r] *= sc;
        }
    }
    #pragma unroll
    for (int r = 0; r < 4; r++){
        int grow = rowbase + q*4 + r;
        if (grow < n_rows){
            #pragma unroll
            for (int tl = 0; tl < 8; tl++)
                Y[(size_t)grow*DD + tl*16 + m] = f2bf(acc[tl][r]);
        }
    }
}

// ---------------- fused mean-aggregate + epilogue (wave per node) ----------------
// h is bf16 (u32 = 2 cols per lane). MODE 0: LeakyReLU  1: expmap0  2: l2norm
template<int MODE>
__global__ void k_agg(const u32* __restrict__ h,
                      const int* __restrict__ row_ptr, const int* __restrict__ sorted_src,
                      const float* __restrict__ invdeg,
                      float* __restrict__ outbuf, int n_rows, const float* __restrict__ cptr){
    int wid = (blockIdx.x*256 + threadIdx.x) >> 6;
    if (wid >= n_rows) return;
    int lane = threadIdx.x & 63;
    int beg = row_ptr[wid], end = row_ptr[wid+1];
    float ax = 0.f, ay = 0.f;
    for (int j0 = beg; j0 < end; j0 += 64){
        int cnt = min(64, end - j0);
        int my = (j0 + lane < end) ? sorted_src[j0 + lane] : 0;
        int k = 0;
        for (; k + 8 <= cnt; k += 8){           // 8 outstanding gathers
            u32 p0 = h[(size_t)__shfl(my, k+0, 64)*64 + lane];
            u32 p1 = h[(size_t)__shfl(my, k+1, 64)*64 + lane];
            u32 p2 = h[(size_t)__shfl(my, k+2, 64)*64 + lane];
            u32 p3 = h[(size_t)__shfl(my, k+3, 64)*64 + lane];
            u32 p4 = h[(size_t)__shfl(my, k+4, 64)*64 + lane];
            u32 p5 = h[(size_t)__shfl(my, k+5, 64)*64 + lane];
            u32 p6 = h[(size_t)__shfl(my, k+6, 64)*64 + lane];
            u32 p7 = h[(size_t)__shfl(my, k+7, 64)*64 + lane];
            ax += lo2f(p0); ay += hi2f(p0);
            ax += lo2f(p1); ay += hi2f(p1);
            ax += lo2f(p2); ay += hi2f(p2);
            ax += lo2f(p3); ay += hi2f(p3);
            ax += lo2f(p4); ay += hi2f(p4);
            ax += lo2f(p5); ay += hi2f(p5);
            ax += lo2f(p6); ay += hi2f(p6);
            ax += lo2f(p7); ay += hi2f(p7);
        }
        for (; k < cnt; k++){
            u32 p = h[(size_t)__shfl(my, k, 64)*64 + lane];
            ax += lo2f(p); ay += hi2f(p);
        }
    }
    float inv = invdeg[wid];
    ax *= inv; ay *= inv;
    float ox, oy;
    if (MODE == 0){
        ox = ax > 0.f ? ax : 0.2f*ax;
        oy = ay > 0.f ? ay : 0.2f*ay;
    } else {
        float ss = ax*ax + ay*ay;
        #pragma unroll
        for (int m = 32; m > 0; m >>= 1) ss += __shfl_xor(ss, m, 64);
        float nrm = sqrtf(ss);
        float scale;
        if (MODE == 1){
            float c  = cptr[0];
            c = (c > 0.f && c < 1e30f) ? c : 1.0f;
            float sc = sqrtf(c);
            float n2 = fmaxf(nrm, 1e-10f);
            scale = tanhf(sc*n2*0.5f) / (sc*n2);
        } else {
            scale = 1.0f / fmaxf(nrm, 1e-12f);
        }
        ox = ax*scale; oy = ay*scale;
    }
    *(float2*)(outbuf + (size_t)wid*DD + lane*2) = make_float2(ox, oy);
}

extern "C" void kernel_launch(void* const* d_in, const int* in_sizes, int n_in,
                              void* d_out, int out_size, void* d_ws, size_t ws_size,
                              hipStream_t stream){
    const int*   src = (const int*)d_in[0];
    const int*   dst = (const int*)d_in[1];
    const float* emb_in[3] = {(const float*)d_in[2], (const float*)d_in[3], (const float*)d_in[4]};
    const float* W_in[3]   = {(const float*)d_in[5], (const float*)d_in[7], (const float*)d_in[9]};
    const float* b_in[3]   = {(const float*)d_in[6], (const float*)d_in[8], (const float*)d_in[10]};
    const float* b_c       = (const float*)d_in[11];

    const int E  = in_sizes[0];
    const int ND = in_sizes[2];
    const int N  = ND / DD;
    const int Lnum = in_sizes[5] / (DD*DD);
    const int nw = Lnum*DD*DD;
    const int nchunks = (N + 511) / 512;

    char* w = (char*)d_ws;
    auto alloc = [&](size_t bytes)->char*{
        char* p = w; w += (bytes + 255) & ~(size_t)255; return p;
    };
    u32*   h         = (u32*)  alloc((size_t)ND*2);     // bf16 h table
    u16*   Wb[3];
    for (int i = 0; i < 3; i++) Wb[i] = (u16*)alloc((size_t)nw*2);
    float* invdeg    = (float*)alloc((size_t)N*4);
    int*   deg       = (int*)  alloc((size_t)N*4);
    int*   row_ptr   = (int*)  alloc((size_t)(N+1)*4);
    int*   cursor    = (int*)  alloc((size_t)N*4);
    int*   csum      = (int*)  alloc((size_t)nchunks*4);
    int*   sorted_src= (int*)  alloc((size_t)E*4);
    (void)ws_size; (void)n_in; (void)out_size;

    float* out_e = (float*)d_out;
    float* out_b = out_e + ND;
    float* out_s = out_e + 2*ND;

    hipMemsetAsync(deg,    0, (size_t)N*4, stream);
    hipMemsetAsync(cursor, 0, (size_t)N*4, stream);

    const int TB = 256;
    for (int i = 0; i < 3; i++)
        k_w2b<<<(nw+TB-1)/TB, TB, 0, stream>>>(W_in[i], Wb[i], nw);

    k_hist<<<(E+TB-1)/TB, TB, 0, stream>>>(dst, deg, E);
    k_chunksum<<<nchunks, 256, 0, stream>>>(deg, csum, invdeg, N);
    k_scanchunks<<<1, 64, 0, stream>>>(csum, nchunks, row_ptr, N);
    k_scanwithin<<<nchunks, 256, 0, stream>>>(deg, csum, row_ptr, N);
    k_fill<<<(E+TB-1)/TB, TB, 0, stream>>>(src, dst, row_ptr, cursor, sorted_src, E);

    const int rowblocks  = (N + 3) / 4;
    const int gemmblocks = (N + 63) / 64;

    const float* se = emb_in[0];
    const float* sb = emb_in[1];
    const float* ss = emb_in[2];

    for (int l = 0; l < Lnum; l++){
        // Euclidean
        k_gemm_mfma<0,0><<<gemmblocks, 256, 0, stream>>>(se, Wb[0] + (size_t)l*DD*DD,
                                                         b_in[0] + (size_t)l*DD, (u16*)h, N, b_c);
        k_agg<0><<<rowblocks, 256, 0, stream>>>(h, row_ptr, sorted_src, invdeg, out_e, N, b_c);
        se = out_e;
        // Hyperbolic (logmap fused into A staging)
        k_gemm_mfma<1,0><<<gemmblocks, 256, 0, stream>>>(sb, Wb[1] + (size_t)l*DD*DD,
                                                         b_in[1] + (size_t)l*DD, (u16*)h, N, b_c);
        k_agg<1><<<rowblocks, 256, 0, stream>>>(h, row_ptr, sorted_src, invdeg, out_b, N, b_c);
        sb = out_b;
        // Spherical (pre-norm fused into A staging, mid-norm fused into epilogue)
        k_gemm_mfma<2,1><<<gemmblocks, 256, 0, stream>>>(ss, Wb[2] + (size_t)l*DD*DD,
                                                         b_in[2] + (size_t)l*DD, (u16*)h, N, b_c);
        k_agg<2><<<rowblocks, 256, 0, stream>>>(h, row_ptr, sorted_src, invdeg, out_s, N, b_c);
        ss = out_s;
    }
}